// Round 10
// baseline (457.401 us; speedup 1.0000x reference)
//
#include <hip/hip_runtime.h>

// GraphAttentionLayer: B=16, N=2048, F_IN=256, H=128 (fp32 in/out, adj int32)
//  k_wh  : MFMA bf16x3-split GEMM wh = X@W^T + bW; fused src/dst dots
//          (log2e + ba folded); writes wh in MFMA B-FRAGMENT order.
//  k_attn: fused pack+attention with HOMOGENEOUS per-wave vmcnt queues
//          (R10 change). R9 lesson: vmcnt is IN-ORDER -- the per-chunk
//          write-late wait for whF staged loads drains every older load in
//          the same wave's queue, killing the adj prefetch distance (real
//          depth was ~1 chunk, k_attn 82.8us vs 43us adj floor). Now:
//          waves 0-1 stage whF only (pure L2 queue); waves 2-3 pack adj
//          only (pure HBM queue -> counted ballot waits at true 3-chunk
//          distance); dst staged to LDS in prologue so the compute path
//          (all 4 waves: weights+8 MFMA per chunk) has ZERO VMEM. Raw
//          {lgkmcnt;s_barrier} per chunk (no vmcnt drain). Mask =
//          raw-ballot layout maskB[bank][word][row] (4KB):
//          bit_j of chunk C = ballot_{j&3} >> (8(C&3)+2q+(j>>2)).

#define BDIM 16
#define NDIM 2048
#define FIN 256
#define HDIM 128
#define LOG2E 1.4426950408889634f

typedef short short8 __attribute__((ext_vector_type(8)));
typedef float floatx4 __attribute__((ext_vector_type(4)));
typedef int intx4 __attribute__((ext_vector_type(4)));

__device__ __forceinline__ unsigned short f2bf(float x) {
    unsigned int u = __float_as_uint(x);
    unsigned int r = (u + 0x7fffu + ((u >> 16) & 1u)) >> 16;  // RNE
    return (unsigned short)r;
}
__device__ __forceinline__ float bf2f(unsigned short s) {
    return __uint_as_float(((unsigned int)s) << 16);
}
__device__ __forceinline__ intx4 ldnt(const int* p) {
    return __builtin_nontemporal_load(reinterpret_cast<const intx4*>(p));
}

// ---------------- Kernel 1: wh via MFMA (bf16 hi/lo split) ----------------
// 64 rows x 128 h per block; 4 waves = 4 m-tiles of 16; K in panels of 64.
__global__ __launch_bounds__(256) void k_wh(const float* __restrict__ X,
                                            const float* __restrict__ W,
                                            const float* __restrict__ bW,
                                            const float* __restrict__ a,
                                            const float* __restrict__ ba_p,
                                            float* __restrict__ src,
                                            float* __restrict__ dst,
                                            unsigned short* __restrict__ whF) {
    __shared__ short lds[27648];                    // 54 KB
    short (*ah)[72] = (short(*)[72])lds;
    short (*al)[72] = (short(*)[72])(lds + 4608);
    short (*bh)[72] = (short(*)[72])(lds + 9216);
    short (*bl)[72] = (short(*)[72])(lds + 18432);
    short (*tb)[72] = (short(*)[72])lds;            // epilogue alias [128][72]

    const int tid = threadIdx.x;
    const long row0 = (long)blockIdx.x * 64;
    const int w = tid >> 6, lane = tid & 63;
    const int lm = lane & 15, q = lane >> 4;
    const float ba0 = ba_p[0];

    float a1v[8], a2v[8], bwv[8];
    #pragma unroll
    for (int nt = 0; nt < 8; nt++) {
        a1v[nt] = a[nt * 16 + lm];
        a2v[nt] = a[HDIM + nt * 16 + lm];
        bwv[nt] = bW[nt * 16 + lm];
    }

    floatx4 acc[8];
    #pragma unroll
    for (int nt = 0; nt < 8; nt++) acc[nt] = (floatx4){0.f, 0.f, 0.f, 0.f};

    for (int k0 = 0; k0 < FIN; k0 += 64) {
        #pragma unroll
        for (int u = 0; u < 4; u++) {
            int idx = tid + u * 256;
            int r = idx >> 4, fc = (idx & 15) * 4;
            float4 v = *reinterpret_cast<const float4*>(X + (row0 + r) * FIN + k0 + fc);
            union { unsigned short s[4]; uint2 u2; } ph, pl;
            ph.s[0] = f2bf(v.x); pl.s[0] = f2bf(v.x - bf2f(ph.s[0]));
            ph.s[1] = f2bf(v.y); pl.s[1] = f2bf(v.y - bf2f(ph.s[1]));
            ph.s[2] = f2bf(v.z); pl.s[2] = f2bf(v.z - bf2f(ph.s[2]));
            ph.s[3] = f2bf(v.w); pl.s[3] = f2bf(v.w - bf2f(ph.s[3]));
            *reinterpret_cast<uint2*>(&ah[r][fc]) = ph.u2;
            *reinterpret_cast<uint2*>(&al[r][fc]) = pl.u2;
        }
        #pragma unroll
        for (int u = 0; u < 8; u++) {
            int idx = tid + u * 256;
            int hh = idx >> 4, fc = (idx & 15) * 4;
            float4 v = *reinterpret_cast<const float4*>(W + hh * FIN + k0 + fc);
            union { unsigned short s[4]; uint2 u2; } ph, pl;
            ph.s[0] = f2bf(v.x); pl.s[0] = f2bf(v.x - bf2f(ph.s[0]));
            ph.s[1] = f2bf(v.y); pl.s[1] = f2bf(v.y - bf2f(ph.s[1]));
            ph.s[2] = f2bf(v.z); pl.s[2] = f2bf(v.z - bf2f(ph.s[2]));
            ph.s[3] = f2bf(v.w); pl.s[3] = f2bf(v.w - bf2f(ph.s[3]));
            *reinterpret_cast<uint2*>(&bh[hh][fc]) = ph.u2;
            *reinterpret_cast<uint2*>(&bl[hh][fc]) = pl.u2;
        }
        __syncthreads();
        #pragma unroll
        for (int ks = 0; ks < 64; ks += 32) {
            short8 afh = *reinterpret_cast<const short8*>(&ah[w * 16 + lm][ks + q * 8]);
            short8 afl = *reinterpret_cast<const short8*>(&al[w * 16 + lm][ks + q * 8]);
            #pragma unroll
            for (int nt = 0; nt < 8; nt++) {
                short8 bfh = *reinterpret_cast<const short8*>(&bh[nt * 16 + lm][ks + q * 8]);
                short8 bfl = *reinterpret_cast<const short8*>(&bl[nt * 16 + lm][ks + q * 8]);
                acc[nt] = __builtin_amdgcn_mfma_f32_16x16x32_bf16(afh, bfh, acc[nt], 0, 0, 0);
                acc[nt] = __builtin_amdgcn_mfma_f32_16x16x32_bf16(afh, bfl, acc[nt], 0, 0, 0);
                acc[nt] = __builtin_amdgcn_mfma_f32_16x16x32_bf16(afl, bfh, acc[nt], 0, 0, 0);
            }
        }
        __syncthreads();
    }

    // epilogue: bias, src/dst dots, transpose via LDS -> B-fragment layout
    float s1[4] = {0.f, 0.f, 0.f, 0.f}, s2[4] = {0.f, 0.f, 0.f, 0.f};
    #pragma unroll
    for (int nt = 0; nt < 8; nt++) {
        #pragma unroll
        for (int r = 0; r < 4; r++) {
            float v = acc[nt][r] + bwv[nt];
            s1[r] += v * a1v[nt];
            s2[r] += v * a2v[nt];
            tb[nt * 16 + lm][w * 16 + q * 4 + r] = f2bf(v);   // tb[h][jrel]
        }
    }
    #pragma unroll
    for (int r = 0; r < 4; r++) {
        #pragma unroll
        for (int o = 1; o < 16; o <<= 1) {
            s1[r] += __shfl_xor(s1[r], o);
            s2[r] += __shfl_xor(s2[r], o);
        }
    }
    if (lm == 0) {
        #pragma unroll
        for (int r = 0; r < 4; r++) {
            long row = row0 + w * 16 + q * 4 + r;
            src[row] = (s1[r] + ba0) * LOG2E;   // fold bias-a + log2e (exp -> exp2)
            dst[row] = s2[r] * LOG2E;
        }
    }
    __syncthreads();
    // whF[b][jc][ht][l][e], frag = 512 shorts; block covers jc0..jc0+1
    const int b = (int)(row0 >> 11);
    const int jc0 = (int)((row0 & 2047) >> 5);
    const int f = tid >> 4;          // 0..15: jcrel = f>>3, ht = f&7
    const int sub = tid & 15;
    const int jcrel = f >> 3, ht = f & 7;
    const size_t fbase = (((size_t)b * 64 + jc0 + jcrel) * 8 + ht) * 512;
    #pragma unroll
    for (int i = 0; i < 4; i++) {
        int l = sub * 4 + i;
        uint4 v = *reinterpret_cast<const uint4*>(&tb[ht * 16 + (l & 15)][jcrel * 32 + (l >> 4) * 8]);
        *reinterpret_cast<uint4*>(whF + fbase + l * 8) = v;
    }
}

// ---------------- Kernel 2: queue-specialized pack + staged attention -----
// 512 blocks (XCD-swizzled) x 256 threads (4 waves). ALL waves compute
// their own 16 i-rows x 128 h. Duties: waves 0-1 stage whF (pure-L2
// queue); waves 2-3 pack adj for 32 rows each (pure-HBM queue).

// Raw barrier: LDS writes visible, VMEM prefetches NOT drained.
#define BAR()                                                                  \
    do {                                                                       \
        asm volatile("s_waitcnt lgkmcnt(0)" ::: "memory");                     \
        __builtin_amdgcn_s_barrier();                                          \
    } while (0)

#define MD_PRE(PW1, BK, HI)                                                    \
    do {                                                                       \
        md[PW1][0] = maskB[BK][0 + (HI)][wrow];                                \
        md[PW1][1] = maskB[BK][2 + (HI)][wrow];                                \
        md[PW1][2] = maskB[BK][4 + (HI)][wrow];                                \
        md[PW1][3] = maskB[BK][6 + (HI)][wrow];                                \
    } while (0)

// Adj duties (waves 2-3 only): subset SUB = 16 rows at aw32+SUB*16.
#define ADJ_ISSUE(G, SUB)                                                      \
    do {                                                                       \
        _Pragma("unroll")                                                      \
        for (int r = 0; r < 16; r++) {                                         \
            const int* ap = adj +                                              \
                (size_t)(rowbase + aw32 + (SUB) * 16 + r) * NDIM +             \
                (G) * 256 + lane * 4;                                          \
            av[r] = ldnt(ap);                                                  \
        }                                                                      \
    } while (0)

#define ADJ_BALLOT(G, SUB)                                                     \
    do {                                                                       \
        _Pragma("unroll")                                                      \
        for (int r = 0; r < 16; r++) {                                         \
            unsigned long long b0 = __ballot(av[r][0] != 0);                   \
            unsigned long long b1 = __ballot(av[r][1] != 0);                   \
            unsigned long long b2 = __ballot(av[r][2] != 0);                   \
            unsigned long long b3 = __ballot(av[r][3] != 0);                   \
            if (lane < 8) {                                                    \
                unsigned long long bb = (lane < 2) ? b0                        \
                                        : (lane < 4) ? b1                      \
                                        : (lane < 6) ? b2 : b3;                \
                unsigned wv = (lane & 1) ? (unsigned)(bb >> 32) : (unsigned)bb;\
                maskB[(G) & 1][lane][aw32 + (SUB) * 16 + r] = wv;              \
            }                                                                  \
        }                                                                      \
    } while (0)

// Chunk C (literal 0..7), T = g8 + C. Duties split by wave class; compute
// path (weights+MFMA) identical on all waves and VMEM-free (dst/md via LDS).
#define CH(C)                                                                  \
    do {                                                                       \
        constexpr int PW = (C) & 1;                                            \
        const int T = g8 + (C);                                                \
        short8 s0, s1, s2, s3;                                                 \
        if (wlow) {                                                            \
            if (T < 63) { /* issue whF stage loads for chunk T+1 (pure L2) */  \
                const unsigned short* gp = gsrc + (size_t)(T + 1) * 4096;      \
                s0 = *reinterpret_cast<const short8*>(gp);                     \
                s1 = *reinterpret_cast<const short8*>(gp + 512);               \
                s2 = *reinterpret_cast<const short8*>(gp + 1024);              \
                s3 = *reinterpret_cast<const short8*>(gp + 1536);              \
            }                                                                  \
        } else { /* adj duties (pure HBM queue, counted waits at ballots) */   \
            if ((C) == 0 && g8 < 56) ADJ_ISSUE((g8 >> 3) + 1, 0);              \
            if ((C) == 3 && g8 < 56) {                                         \
                ADJ_BALLOT((g8 >> 3) + 1, 0);                                  \
                ADJ_ISSUE((g8 >> 3) + 1, 1);                                   \
            }                                                                  \
            if ((C) == 6 && g8 < 56) ADJ_BALLOT((g8 >> 3) + 1, 1);             \
        }                                                                      \
        if (T < 63) { /* dst (LDS) + mask dword (LDS) prefetch for T+1 */      \
            d[PW ^ 1][0] =                                                     \
                *reinterpret_cast<const floatx4*>(&dstS[(T + 1) * 32 + q8]);   \
            d[PW ^ 1][1] =                                                     \
                *reinterpret_cast<const floatx4*>(&dstS[(T + 1) * 32 + q8 + 4]); \
            if ((C) < 7) {                                                     \
                MD_PRE(PW ^ 1, (g8 >> 3) & 1, (((C) + 1) & 4) ? 1 : 0);        \
            } else {                                                           \
                MD_PRE(PW ^ 1, ((g8 >> 3) + 1) & 1, 0);                        \
            }                                                                  \
        }                                                                      \
        const int base = 8 * ((C) & 3) + 2 * q;                                \
        short8 af;                                                             \
        _Pragma("unroll")                                                      \
        for (int j = 0; j < 8; j++) {                                          \
            float x = si + d[PW][j >> 2][j & 3];                               \
            x = fmaxf(x, 0.01f * x);            /* leaky, scale-invariant */   \
            float e2 = __builtin_amdgcn_exp2f(x);                              \
            unsigned bit = (md[PW][j & 3] >> (base + (j >> 2))) & 1u;          \
            float wgt = bit ? e2 : 0.f;                                        \
            lpart += wgt;                                                      \
            af[j] = (short)f2bf(wgt);                                          \
        }                                                                      \
        _Pragma("unroll")                                                      \
        for (int hj = 0; hj < 8; hj++) {                                       \
            short8 fb = *reinterpret_cast<const short8*>(                      \
                &whS[PW][hj * 512 + lane * 8]);                                \
            acc[hj] = __builtin_amdgcn_mfma_f32_16x16x32_bf16(af, fb,          \
                                                              acc[hj], 0, 0, 0); \
        }                                                                      \
        if (wlow && T < 63) { /* write-late (waits only own whF loads) */      \
            short* lp = &whS[PW ^ 1][pofs];                                    \
            *reinterpret_cast<short8*>(lp) = s0;                               \
            *reinterpret_cast<short8*>(lp + 512) = s1;                         \
            *reinterpret_cast<short8*>(lp + 1024) = s2;                        \
            *reinterpret_cast<short8*>(lp + 1536) = s3;                        \
        }                                                                      \
        BAR();                                                                 \
    } while (0)

__global__ __launch_bounds__(256) void k_attn(const int* __restrict__ adj,
                                              const unsigned short* __restrict__ whF,
                                              const float* __restrict__ src,
                                              const float* __restrict__ dst,
                                              float* __restrict__ out) {
    __shared__ short whS[2][4096];       // 16 KB: staged whF chunk dbuf
    __shared__ unsigned maskB[2][8][65]; // 4.1 KB: raw-ballot mask dbuf
    __shared__ float dstS[2048];         // 8 KB: dst row (whole batch slice)
    __shared__ float lred[64];
    __shared__ float linv_s[64];

    const int tid = threadIdx.x;
    // XCD swizzle: 512 blocks, 8 XCDs -> XCD k gets a contiguous 64-block
    // chunk = batches 2k,2k+1. whF working set/XCD: 1 MB (L2-resident).
    const int bid = ((int)blockIdx.x & 7) * 64 + ((int)blockIdx.x >> 3);
    const int b = bid >> 5;                   // 32 i-tiles per batch
    const int i0 = (bid & 31) * 64;
    const int wave = tid >> 6, lane = tid & 63;
    const bool wlow = wave < 2;               // whF-staging waves
    const int aw32 = (wave & 1) * 32;         // adj-wave row base (waves 2-3)
    const int lm = lane & 15, q = lane >> 4;
    const int q8 = q * 8;
    const int wrow = wave * 16 + lm;          // local i-row this lane owns
    const int rowbase = b * NDIM + i0;

    const float si = src[rowbase + wrow];     // includes ba and log2e scale
    // whF staging (waves 0-1): chunk = 4096 shorts; wave w covers
    // shorts [w*2048, +2048) via 4 x short8 segments.
    const unsigned short* gsrc =
        whF + (size_t)b * 262144 + wave * 2048 + lane * 8;
    const int pofs = wave * 2048 + lane * 8;

    floatx4 acc[8];
    #pragma unroll
    for (int hj = 0; hj < 8; hj++) acc[hj] = (floatx4){0.f, 0.f, 0.f, 0.f};
    float lpart = 0.f;

    unsigned md[2][4];      // mask dwords dbuf (LDS-sourced)
    floatx4 d[2][2];        // dst dbuf (LDS-sourced)
    intx4 av[16];           // adj in-flight rows (waves 2-3; 16 rows/subset)

    // prologue: dstS (all); whS chunk 0 (waves 0-1); pack group 0 (waves 2-3)
    {
        const float* dg = dst + b * NDIM;
        *reinterpret_cast<float4*>(&dstS[tid * 8]) =
            *reinterpret_cast<const float4*>(dg + tid * 8);
        *reinterpret_cast<float4*>(&dstS[tid * 8 + 4]) =
            *reinterpret_cast<const float4*>(dg + tid * 8 + 4);
    }
    if (wlow) {
        short8 p0 = *reinterpret_cast<const short8*>(gsrc);
        short8 p1 = *reinterpret_cast<const short8*>(gsrc + 512);
        short8 p2 = *reinterpret_cast<const short8*>(gsrc + 1024);
        short8 p3 = *reinterpret_cast<const short8*>(gsrc + 1536);
        short* lp = &whS[0][pofs];
        *reinterpret_cast<short8*>(lp) = p0;
        *reinterpret_cast<short8*>(lp + 512) = p1;
        *reinterpret_cast<short8*>(lp + 1024) = p2;
        *reinterpret_cast<short8*>(lp + 1536) = p3;
    } else {
        ADJ_ISSUE(0, 0);
        ADJ_BALLOT(0, 0);
        ADJ_ISSUE(0, 1);
        ADJ_BALLOT(0, 1);
    }
    __syncthreads();
    MD_PRE(0, 0, 0);   // chunk 0: bank 0, hi 0
    d[0][0] = *reinterpret_cast<const floatx4*>(&dstS[q8]);
    d[0][1] = *reinterpret_cast<const floatx4*>(&dstS[q8 + 4]);

    for (int g8 = 0; g8 < 64; g8 += 8) {
        CH(0); CH(1); CH(2); CH(3);
        CH(4); CH(5); CH(6); CH(7);
    }

    // denominator: combine the 4 q-slices of each row
    lpart += __shfl_xor(lpart, 16);
    lpart += __shfl_xor(lpart, 32);
    if (q == 0) lred[wrow] = lpart;
    __syncthreads();
    if (tid < 64) {
        float l = lred[tid];
        linv_s[tid] = l > 0.f ? 1.f / l : 0.f;
    }
    __syncthreads();

    // epilogue: scale 1/l, ELU, store (C/D: col=lm -> h, row=q*4+r -> i)
    #pragma unroll
    for (int r = 0; r < 4; r++) {
        int il = wave * 16 + q * 4 + r;
        float li = linv_s[il];
        size_t obase = ((size_t)(rowbase + il)) * HDIM + lm;
        #pragma unroll
        for (int hj = 0; hj < 8; hj++) {
            float x = acc[hj][r] * li;
            x = x > 0.f ? x : (__expf(x) - 1.f);
            out[obase + hj * 16] = x;
        }
    }
}

extern "C" void kernel_launch(void* const* d_in, const int* in_sizes, int n_in,
                              void* d_out, int out_size, void* d_ws, size_t ws_size,
                              hipStream_t stream) {
    const float* X  = (const float*)d_in[0];   // [16,2048,256]
    const int* adj  = (const int*)d_in[1];     // [16,2048,2048]
    const float* W  = (const float*)d_in[2];   // [128,256]
    const float* bW = (const float*)d_in[3];   // [128]
    const float* a  = (const float*)d_in[4];   // [1,256]
    const float* ba = (const float*)d_in[5];   // [1]
    float* out = (float*)d_out;                // [16,2048,128]

    float* srcv = (float*)d_ws;                                    // B*N
    float* dstv = srcv + BDIM * NDIM;                              // B*N
    unsigned short* whF = (unsigned short*)(dstv + BDIM * NDIM);   // 8.4 MB bf16 frag-order

    k_wh<<<BDIM * NDIM / 64, 256, 0, stream>>>(X, W, bW, a, ba, srcv, dstv, whF);
    k_attn<<<BDIM * (NDIM / 64), 256, 0, stream>>>(adj, whF, srcv, dstv, out);
}

// Round 11
// 408.039 us; speedup vs baseline: 1.1210x; 1.1210x over previous
//
#include <hip/hip_runtime.h>
#include <hip/hip_bf16.h>

// GraphAttentionLayer: B=16, N=2048, F_IN=256, H=128 (fp32 in/out, adj int32)
//  k_wh  : MFMA bf16x3-split GEMM wh = X@W^T + bW; fused src/dst dots
//          (log2e + ba folded); writes wh in MFMA B-FRAGMENT order.
//  k_attn: R9 structure (best: 410.6) + two deltas. R10's queue
//          specialization (av[16], split waves) regressed 47us -- reverted.
//          Delta 1: af bf16 pack via __float2bfloat16 (hardware
//          v_cvt_pk_bf16_f32; RNE, same numerics) instead of 5-op manual
//          RNE -- cuts weights VALU ~35% (testing the "loop is VALU-bound"
//          theory; 3 structures all sat ~45us vs ~18us issue model).
//          Delta 2: dst staged to LDS in prologue -- per-chunk vmcnt queue
//          now only whF (+ adj at C0/C3), shorter counted-wait chains.
//          Raw {lgkmcnt;s_barrier} per chunk (no vmcnt drain). Mask =
//          raw-ballot layout maskB[bank][word][row] (4KB):
//          bit_j of chunk C = ballot_{j&3} >> (8(C&3)+2q+(j>>2)).

#define BDIM 16
#define NDIM 2048
#define FIN 256
#define HDIM 128
#define LOG2E 1.4426950408889634f

typedef short short8 __attribute__((ext_vector_type(8)));
typedef float floatx4 __attribute__((ext_vector_type(4)));
typedef int intx4 __attribute__((ext_vector_type(4)));

__device__ __forceinline__ unsigned short f2bf(float x) {
    unsigned int u = __float_as_uint(x);
    unsigned int r = (u + 0x7fffu + ((u >> 16) & 1u)) >> 16;  // RNE
    return (unsigned short)r;
}
__device__ __forceinline__ float bf2f(unsigned short s) {
    return __uint_as_float(((unsigned int)s) << 16);
}
__device__ __forceinline__ intx4 ldnt(const int* p) {
    return __builtin_nontemporal_load(reinterpret_cast<const intx4*>(p));
}

// ---------------- Kernel 1: wh via MFMA (bf16 hi/lo split) ----------------
// 64 rows x 128 h per block; 4 waves = 4 m-tiles of 16; K in panels of 64.
__global__ __launch_bounds__(256) void k_wh(const float* __restrict__ X,
                                            const float* __restrict__ W,
                                            const float* __restrict__ bW,
                                            const float* __restrict__ a,
                                            const float* __restrict__ ba_p,
                                            float* __restrict__ src,
                                            float* __restrict__ dst,
                                            unsigned short* __restrict__ whF) {
    __shared__ short lds[27648];                    // 54 KB
    short (*ah)[72] = (short(*)[72])lds;
    short (*al)[72] = (short(*)[72])(lds + 4608);
    short (*bh)[72] = (short(*)[72])(lds + 9216);
    short (*bl)[72] = (short(*)[72])(lds + 18432);
    short (*tb)[72] = (short(*)[72])lds;            // epilogue alias [128][72]

    const int tid = threadIdx.x;
    const long row0 = (long)blockIdx.x * 64;
    const int w = tid >> 6, lane = tid & 63;
    const int lm = lane & 15, q = lane >> 4;
    const float ba0 = ba_p[0];

    float a1v[8], a2v[8], bwv[8];
    #pragma unroll
    for (int nt = 0; nt < 8; nt++) {
        a1v[nt] = a[nt * 16 + lm];
        a2v[nt] = a[HDIM + nt * 16 + lm];
        bwv[nt] = bW[nt * 16 + lm];
    }

    floatx4 acc[8];
    #pragma unroll
    for (int nt = 0; nt < 8; nt++) acc[nt] = (floatx4){0.f, 0.f, 0.f, 0.f};

    for (int k0 = 0; k0 < FIN; k0 += 64) {
        #pragma unroll
        for (int u = 0; u < 4; u++) {
            int idx = tid + u * 256;
            int r = idx >> 4, fc = (idx & 15) * 4;
            float4 v = *reinterpret_cast<const float4*>(X + (row0 + r) * FIN + k0 + fc);
            union { unsigned short s[4]; uint2 u2; } ph, pl;
            ph.s[0] = f2bf(v.x); pl.s[0] = f2bf(v.x - bf2f(ph.s[0]));
            ph.s[1] = f2bf(v.y); pl.s[1] = f2bf(v.y - bf2f(ph.s[1]));
            ph.s[2] = f2bf(v.z); pl.s[2] = f2bf(v.z - bf2f(ph.s[2]));
            ph.s[3] = f2bf(v.w); pl.s[3] = f2bf(v.w - bf2f(ph.s[3]));
            *reinterpret_cast<uint2*>(&ah[r][fc]) = ph.u2;
            *reinterpret_cast<uint2*>(&al[r][fc]) = pl.u2;
        }
        #pragma unroll
        for (int u = 0; u < 8; u++) {
            int idx = tid + u * 256;
            int hh = idx >> 4, fc = (idx & 15) * 4;
            float4 v = *reinterpret_cast<const float4*>(W + hh * FIN + k0 + fc);
            union { unsigned short s[4]; uint2 u2; } ph, pl;
            ph.s[0] = f2bf(v.x); pl.s[0] = f2bf(v.x - bf2f(ph.s[0]));
            ph.s[1] = f2bf(v.y); pl.s[1] = f2bf(v.y - bf2f(ph.s[1]));
            ph.s[2] = f2bf(v.z); pl.s[2] = f2bf(v.z - bf2f(ph.s[2]));
            ph.s[3] = f2bf(v.w); pl.s[3] = f2bf(v.w - bf2f(ph.s[3]));
            *reinterpret_cast<uint2*>(&bh[hh][fc]) = ph.u2;
            *reinterpret_cast<uint2*>(&bl[hh][fc]) = pl.u2;
        }
        __syncthreads();
        #pragma unroll
        for (int ks = 0; ks < 64; ks += 32) {
            short8 afh = *reinterpret_cast<const short8*>(&ah[w * 16 + lm][ks + q * 8]);
            short8 afl = *reinterpret_cast<const short8*>(&al[w * 16 + lm][ks + q * 8]);
            #pragma unroll
            for (int nt = 0; nt < 8; nt++) {
                short8 bfh = *reinterpret_cast<const short8*>(&bh[nt * 16 + lm][ks + q * 8]);
                short8 bfl = *reinterpret_cast<const short8*>(&bl[nt * 16 + lm][ks + q * 8]);
                acc[nt] = __builtin_amdgcn_mfma_f32_16x16x32_bf16(afh, bfh, acc[nt], 0, 0, 0);
                acc[nt] = __builtin_amdgcn_mfma_f32_16x16x32_bf16(afh, bfl, acc[nt], 0, 0, 0);
                acc[nt] = __builtin_amdgcn_mfma_f32_16x16x32_bf16(afl, bfh, acc[nt], 0, 0, 0);
            }
        }
        __syncthreads();
    }

    // epilogue: bias, src/dst dots, transpose via LDS -> B-fragment layout
    float s1[4] = {0.f, 0.f, 0.f, 0.f}, s2[4] = {0.f, 0.f, 0.f, 0.f};
    #pragma unroll
    for (int nt = 0; nt < 8; nt++) {
        #pragma unroll
        for (int r = 0; r < 4; r++) {
            float v = acc[nt][r] + bwv[nt];
            s1[r] += v * a1v[nt];
            s2[r] += v * a2v[nt];
            tb[nt * 16 + lm][w * 16 + q * 4 + r] = f2bf(v);   // tb[h][jrel]
        }
    }
    #pragma unroll
    for (int r = 0; r < 4; r++) {
        #pragma unroll
        for (int o = 1; o < 16; o <<= 1) {
            s1[r] += __shfl_xor(s1[r], o);
            s2[r] += __shfl_xor(s2[r], o);
        }
    }
    if (lm == 0) {
        #pragma unroll
        for (int r = 0; r < 4; r++) {
            long row = row0 + w * 16 + q * 4 + r;
            src[row] = (s1[r] + ba0) * LOG2E;   // fold bias-a + log2e (exp -> exp2)
            dst[row] = s2[r] * LOG2E;
        }
    }
    __syncthreads();
    // whF[b][jc][ht][l][e], frag = 512 shorts; block covers jc0..jc0+1
    const int b = (int)(row0 >> 11);
    const int jc0 = (int)((row0 & 2047) >> 5);
    const int f = tid >> 4;          // 0..15: jcrel = f>>3, ht = f&7
    const int sub = tid & 15;
    const int jcrel = f >> 3, ht = f & 7;
    const size_t fbase = (((size_t)b * 64 + jc0 + jcrel) * 8 + ht) * 512;
    #pragma unroll
    for (int i = 0; i < 4; i++) {
        int l = sub * 4 + i;
        uint4 v = *reinterpret_cast<const uint4*>(&tb[ht * 16 + (l & 15)][jcrel * 32 + (l >> 4) * 8]);
        *reinterpret_cast<uint4*>(whF + fbase + l * 8) = v;
    }
}

// ---------------- Kernel 2: merged pack + LDS-staged MFMA attention -------
// 512 blocks (XCD-swizzled) x 256 threads (4 waves). Wave w owns i-rows
// i0+w*16..+15 AND packs those rows' adj, pipelined one 8-chunk group ahead.

// Raw barrier: LDS writes visible, VMEM prefetches NOT drained.
#define BAR()                                                                  \
    do {                                                                       \
        asm volatile("s_waitcnt lgkmcnt(0)" ::: "memory");                     \
        __builtin_amdgcn_s_barrier();                                          \
    } while (0)

#define MD_PRE(PW1, BK, HI)                                                    \
    do {                                                                       \
        md[PW1][0] = maskB[BK][0 + (HI)][wrow];                                \
        md[PW1][1] = maskB[BK][2 + (HI)][wrow];                                \
        md[PW1][2] = maskB[BK][4 + (HI)][wrow];                                \
        md[PW1][3] = maskB[BK][6 + (HI)][wrow];                                \
    } while (0)

#define ADJ_ISSUE(GNEXT, H)                                                    \
    do {                                                                       \
        _Pragma("unroll")                                                      \
        for (int r = 0; r < 8; r++) {                                          \
            const int* ap = adj +                                              \
                (size_t)(rowbase + wave * 16 + (H) * 8 + r) * NDIM +           \
                (GNEXT) * 256 + lane * 4;                                      \
            av[r] = ldnt(ap);                                                  \
        }                                                                      \
    } while (0)

#define ADJ_BALLOT(GNEXT, H)                                                   \
    do {                                                                       \
        _Pragma("unroll")                                                      \
        for (int r = 0; r < 8; r++) {                                          \
            unsigned long long b0 = __ballot(av[r][0] != 0);                   \
            unsigned long long b1 = __ballot(av[r][1] != 0);                   \
            unsigned long long b2 = __ballot(av[r][2] != 0);                   \
            unsigned long long b3 = __ballot(av[r][3] != 0);                   \
            if (lane < 8) {                                                    \
                unsigned long long bb = (lane < 2) ? b0                        \
                                        : (lane < 4) ? b1                      \
                                        : (lane < 6) ? b2 : b3;                \
                unsigned wv = (lane & 1) ? (unsigned)(bb >> 32) : (unsigned)bb;\
                maskB[(GNEXT) & 1][lane][wave * 16 + (H) * 8 + r] = wv;        \
            }                                                                  \
        }                                                                      \
    } while (0)

// Merged chunk C (literal 0..7), T = g8 + C.
// Order: whF issue -> adj duties (counted waits; queue = whF + periodic
// adj only, dst/md are LDS) -> dst/md prefetch (LDS) -> weights+MFMA ->
// write-late -> raw barrier.
#define CH(C)                                                                  \
    do {                                                                       \
        constexpr int PW = (C) & 1;                                            \
        const int T = g8 + (C);                                                \
        short8 s0, s1;                                                         \
        if (T < 63) { /* issue whF stage loads for chunk T+1 */                \
            const unsigned short* gp = gsrc + (size_t)(T + 1) * 4096;          \
            s0 = *reinterpret_cast<const short8*>(gp);                         \
            s1 = *reinterpret_cast<const short8*>(gp + 512);                   \
        }                                                                      \
        if ((C) == 0 && g8 < 56) ADJ_ISSUE((g8 >> 3) + 1, 0);                  \
        if ((C) == 3 && g8 < 56) {                                             \
            ADJ_BALLOT((g8 >> 3) + 1, 0);                                      \
            ADJ_ISSUE((g8 >> 3) + 1, 1);                                       \
        }                                                                      \
        if ((C) == 6 && g8 < 56) ADJ_BALLOT((g8 >> 3) + 1, 1);                 \
        if (T < 63) { /* dst (LDS) + mask dword (LDS) prefetch for T+1 */      \
            d[PW ^ 1][0] =                                                     \
                *reinterpret_cast<const floatx4*>(&dstS[(T + 1) * 32 + q8]);   \
            d[PW ^ 1][1] =                                                     \
                *reinterpret_cast<const floatx4*>(&dstS[(T + 1) * 32 + q8 + 4]); \
            if ((C) < 7) {                                                     \
                MD_PRE(PW ^ 1, (g8 >> 3) & 1, (((C) + 1) & 4) ? 1 : 0);        \
            } else {                                                           \
                MD_PRE(PW ^ 1, ((g8 >> 3) + 1) & 1, 0);                        \
            }                                                                  \
        }                                                                      \
        const int base = 8 * ((C) & 3) + 2 * q;                                \
        short8 af;                                                             \
        _Pragma("unroll")                                                      \
        for (int j = 0; j < 8; j++) {                                          \
            float x = si + d[PW][j >> 2][j & 3];                               \
            x = fmaxf(x, 0.01f * x);            /* leaky, scale-invariant */   \
            float e2 = __builtin_amdgcn_exp2f(x);                              \
            unsigned bit = (md[PW][j & 3] >> (base + (j >> 2))) & 1u;          \
            float wgt = bit ? e2 : 0.f;                                        \
            lpart += wgt;                                                      \
            __hip_bfloat16 hb = __float2bfloat16(wgt); /* HW cvt_pk, RNE */    \
            af[j] = *reinterpret_cast<short*>(&hb);                            \
        }                                                                      \
        _Pragma("unroll")                                                      \
        for (int hj = 0; hj < 8; hj++) {                                       \
            short8 fb = *reinterpret_cast<const short8*>(                      \
                &whS[PW][hj * 512 + lane * 8]);                                \
            acc[hj] = __builtin_amdgcn_mfma_f32_16x16x32_bf16(af, fb,          \
                                                              acc[hj], 0, 0, 0); \
        }                                                                      \
        if (T < 63) { /* write-late: staged whF -> other LDS buffer */         \
            *reinterpret_cast<short8*>(&whS[PW ^ 1][pofs]) = s0;               \
            *reinterpret_cast<short8*>(&whS[PW ^ 1][pofs + 512]) = s1;         \
        }                                                                      \
        BAR();                                                                 \
    } while (0)

__global__ __launch_bounds__(256) void k_attn(const int* __restrict__ adj,
                                              const unsigned short* __restrict__ whF,
                                              const float* __restrict__ src,
                                              const float* __restrict__ dst,
                                              float* __restrict__ out) {
    __shared__ short whS[2][4096];       // 16 KB: staged whF chunk dbuf
    __shared__ unsigned maskB[2][8][65]; // 4.1 KB: raw-ballot mask dbuf
    __shared__ float dstS[2048];         // 8 KB: dst batch-slice (prologue)
    __shared__ float lred[64];
    __shared__ float linv_s[64];

    const int tid = threadIdx.x;
    // XCD swizzle: 512 blocks, 8 XCDs -> XCD k gets a contiguous 64-block
    // chunk = batches 2k,2k+1. whF working set/XCD: 1 MB (L2-resident).
    const int bid = ((int)blockIdx.x & 7) * 64 + ((int)blockIdx.x >> 3);
    const int b = bid >> 5;                   // 32 i-tiles per batch
    const int i0 = (bid & 31) * 64;
    const int wave = tid >> 6, lane = tid & 63;
    const int lm = lane & 15, q = lane >> 4;
    const int q8 = q * 8;
    const int wrow = wave * 16 + lm;          // local i-row this lane owns
    const int rowbase = b * NDIM + i0;

    const float si = src[rowbase + wrow];     // includes ba and log2e scale
    // staging: chunk = 4096 shorts; wave w copies shorts [w*1024, +1024)
    const unsigned short* gsrc =
        whF + (size_t)b * 262144 + wave * 1024 + lane * 8;
    const int pofs = wave * 1024 + lane * 8;

    floatx4 acc[8];
    #pragma unroll
    for (int hj = 0; hj < 8; hj++) acc[hj] = (floatx4){0.f, 0.f, 0.f, 0.f};
    float lpart = 0.f;

    unsigned md[2][4];      // mask dwords dbuf (LDS-sourced)
    floatx4 d[2][2];        // dst dbuf (LDS-sourced)
    intx4 av[8];            // adj in-flight rows (8 rows x 256 cols)

    // prologue: dstS (all); whS chunk 0; pack group 0; d slot 0.
    {
        const float* dg = dst + b * NDIM;
        *reinterpret_cast<float4*>(&dstS[tid * 8]) =
            *reinterpret_cast<const float4*>(dg + tid * 8);
        *reinterpret_cast<float4*>(&dstS[tid * 8 + 4]) =
            *reinterpret_cast<const float4*>(dg + tid * 8 + 4);
    }
    {
        short8 p0 = *reinterpret_cast<const short8*>(gsrc);
        short8 p1 = *reinterpret_cast<const short8*>(gsrc + 512);
        *reinterpret_cast<short8*>(&whS[0][pofs]) = p0;
        *reinterpret_cast<short8*>(&whS[0][pofs + 512]) = p1;
    }
    ADJ_ISSUE(0, 0);
    ADJ_BALLOT(0, 0);
    ADJ_ISSUE(0, 1);
    ADJ_BALLOT(0, 1);
    __syncthreads();
    MD_PRE(0, 0, 0);   // chunk 0: bank 0, hi 0
    d[0][0] = *reinterpret_cast<const floatx4*>(&dstS[q8]);
    d[0][1] = *reinterpret_cast<const floatx4*>(&dstS[q8 + 4]);

    for (int g8 = 0; g8 < 64; g8 += 8) {
        CH(0); CH(1); CH(2); CH(3);
        CH(4); CH(5); CH(6); CH(7);
    }

    // denominator: combine the 4 q-slices of each row
    lpart += __shfl_xor(lpart, 16);
    lpart += __shfl_xor(lpart, 32);
    if (q == 0) lred[wrow] = lpart;
    __syncthreads();
    if (tid < 64) {
        float l = lred[tid];
        linv_s[tid] = l > 0.f ? 1.f / l : 0.f;
    }
    __syncthreads();

    // epilogue: scale 1/l, ELU, store (C/D: col=lm -> h, row=q*4+r -> i)
    #pragma unroll
    for (int r = 0; r < 4; r++) {
        int il = wave * 16 + q * 4 + r;
        float li = linv_s[il];
        size_t obase = ((size_t)(rowbase + il)) * HDIM + lm;
        #pragma unroll
        for (int hj = 0; hj < 8; hj++) {
            float x = acc[hj][r] * li;
            x = x > 0.f ? x : (__expf(x) - 1.f);
            out[obase + hj * 16] = x;
        }
    }
}

extern "C" void kernel_launch(void* const* d_in, const int* in_sizes, int n_in,
                              void* d_out, int out_size, void* d_ws, size_t ws_size,
                              hipStream_t stream) {
    const float* X  = (const float*)d_in[0];   // [16,2048,256]
    const int* adj  = (const int*)d_in[1];     // [16,2048,2048]
    const float* W  = (const float*)d_in[2];   // [128,256]
    const float* bW = (const float*)d_in[3];   // [128]
    const float* a  = (const float*)d_in[4];   // [1,256]
    const float* ba = (const float*)d_in[5];   // [1]
    float* out = (float*)d_out;                // [16,2048,128]

    float* srcv = (float*)d_ws;                                    // B*N
    float* dstv = srcv + BDIM * NDIM;                              // B*N
    unsigned short* whF = (unsigned short*)(dstv + BDIM * NDIM);   // 8.4 MB bf16 frag-order

    k_wh<<<BDIM * NDIM / 64, 256, 0, stream>>>(X, W, bW, a, ba, srcv, dstv, whF);
    k_attn<<<BDIM * (NDIM / 64), 256, 0, stream>>>(adj, whF, srcv, dstv, out);
}

// Round 12
// 397.693 us; speedup vs baseline: 1.1501x; 1.0260x over previous
//
#include <hip/hip_runtime.h>
#include <hip/hip_bf16.h>

// GraphAttentionLayer: B=16, N=2048, F_IN=256, H=128 (fp32 in/out, adj int32)
//  k_wh  : MFMA bf16x3-split GEMM wh = X@W^T + bW; fused src/dst dots
//          (log2e + ba folded); writes wh in MFMA B-FRAGMENT order.
//  k_attn: R11 base + PAIR schedule (R12): 2 chunks per barrier, whS
//          4-deep (32KB). Queue discipline per pair: whF loads for T+2/T+3
//          issued FIRST, adj bursts right after (adj NEWER than the whF
//          the write-late waits on -> vmcnt(8) keeps adj in flight; R11
//          leaked here: C==1's write drained C==0's adj at age ~1 chunk).
//          Ballots run 2-4 chunks after issue (~800-1600cy > HBM ~900).
//          Barriers 64->32 (exposed at 2 waves/SIMD). md/d read direct
//          from LDS (dbuf dropped). Raw {lgkmcnt;s_barrier}. Mask =
//          raw-ballot layout maskB[bank][word][row] (4KB):
//          bit_j of chunk C = ballot_{j&3} >> (8(C&3)+2q+(j>>2)).

#define BDIM 16
#define NDIM 2048
#define FIN 256
#define HDIM 128
#define LOG2E 1.4426950408889634f

typedef short short8 __attribute__((ext_vector_type(8)));
typedef float floatx4 __attribute__((ext_vector_type(4)));
typedef int intx4 __attribute__((ext_vector_type(4)));

__device__ __forceinline__ unsigned short f2bf(float x) {
    unsigned int u = __float_as_uint(x);
    unsigned int r = (u + 0x7fffu + ((u >> 16) & 1u)) >> 16;  // RNE
    return (unsigned short)r;
}
__device__ __forceinline__ float bf2f(unsigned short s) {
    return __uint_as_float(((unsigned int)s) << 16);
}
__device__ __forceinline__ intx4 ldnt(const int* p) {
    return __builtin_nontemporal_load(reinterpret_cast<const intx4*>(p));
}

// ---------------- Kernel 1: wh via MFMA (bf16 hi/lo split) ----------------
// 64 rows x 128 h per block; 4 waves = 4 m-tiles of 16; K in panels of 64.
__global__ __launch_bounds__(256) void k_wh(const float* __restrict__ X,
                                            const float* __restrict__ W,
                                            const float* __restrict__ bW,
                                            const float* __restrict__ a,
                                            const float* __restrict__ ba_p,
                                            float* __restrict__ src,
                                            float* __restrict__ dst,
                                            unsigned short* __restrict__ whF) {
    __shared__ short lds[27648];                    // 54 KB
    short (*ah)[72] = (short(*)[72])lds;
    short (*al)[72] = (short(*)[72])(lds + 4608);
    short (*bh)[72] = (short(*)[72])(lds + 9216);
    short (*bl)[72] = (short(*)[72])(lds + 18432);
    short (*tb)[72] = (short(*)[72])lds;            // epilogue alias [128][72]

    const int tid = threadIdx.x;
    const long row0 = (long)blockIdx.x * 64;
    const int w = tid >> 6, lane = tid & 63;
    const int lm = lane & 15, q = lane >> 4;
    const float ba0 = ba_p[0];

    float a1v[8], a2v[8], bwv[8];
    #pragma unroll
    for (int nt = 0; nt < 8; nt++) {
        a1v[nt] = a[nt * 16 + lm];
        a2v[nt] = a[HDIM + nt * 16 + lm];
        bwv[nt] = bW[nt * 16 + lm];
    }

    floatx4 acc[8];
    #pragma unroll
    for (int nt = 0; nt < 8; nt++) acc[nt] = (floatx4){0.f, 0.f, 0.f, 0.f};

    for (int k0 = 0; k0 < FIN; k0 += 64) {
        #pragma unroll
        for (int u = 0; u < 4; u++) {
            int idx = tid + u * 256;
            int r = idx >> 4, fc = (idx & 15) * 4;
            float4 v = *reinterpret_cast<const float4*>(X + (row0 + r) * FIN + k0 + fc);
            union { unsigned short s[4]; uint2 u2; } ph, pl;
            ph.s[0] = f2bf(v.x); pl.s[0] = f2bf(v.x - bf2f(ph.s[0]));
            ph.s[1] = f2bf(v.y); pl.s[1] = f2bf(v.y - bf2f(ph.s[1]));
            ph.s[2] = f2bf(v.z); pl.s[2] = f2bf(v.z - bf2f(ph.s[2]));
            ph.s[3] = f2bf(v.w); pl.s[3] = f2bf(v.w - bf2f(ph.s[3]));
            *reinterpret_cast<uint2*>(&ah[r][fc]) = ph.u2;
            *reinterpret_cast<uint2*>(&al[r][fc]) = pl.u2;
        }
        #pragma unroll
        for (int u = 0; u < 8; u++) {
            int idx = tid + u * 256;
            int hh = idx >> 4, fc = (idx & 15) * 4;
            float4 v = *reinterpret_cast<const float4*>(W + hh * FIN + k0 + fc);
            union { unsigned short s[4]; uint2 u2; } ph, pl;
            ph.s[0] = f2bf(v.x); pl.s[0] = f2bf(v.x - bf2f(ph.s[0]));
            ph.s[1] = f2bf(v.y); pl.s[1] = f2bf(v.y - bf2f(ph.s[1]));
            ph.s[2] = f2bf(v.z); pl.s[2] = f2bf(v.z - bf2f(ph.s[2]));
            ph.s[3] = f2bf(v.w); pl.s[3] = f2bf(v.w - bf2f(ph.s[3]));
            *reinterpret_cast<uint2*>(&bh[hh][fc]) = ph.u2;
            *reinterpret_cast<uint2*>(&bl[hh][fc]) = pl.u2;
        }
        __syncthreads();
        #pragma unroll
        for (int ks = 0; ks < 64; ks += 32) {
            short8 afh = *reinterpret_cast<const short8*>(&ah[w * 16 + lm][ks + q * 8]);
            short8 afl = *reinterpret_cast<const short8*>(&al[w * 16 + lm][ks + q * 8]);
            #pragma unroll
            for (int nt = 0; nt < 8; nt++) {
                short8 bfh = *reinterpret_cast<const short8*>(&bh[nt * 16 + lm][ks + q * 8]);
                short8 bfl = *reinterpret_cast<const short8*>(&bl[nt * 16 + lm][ks + q * 8]);
                acc[nt] = __builtin_amdgcn_mfma_f32_16x16x32_bf16(afh, bfh, acc[nt], 0, 0, 0);
                acc[nt] = __builtin_amdgcn_mfma_f32_16x16x32_bf16(afh, bfl, acc[nt], 0, 0, 0);
                acc[nt] = __builtin_amdgcn_mfma_f32_16x16x32_bf16(afl, bfh, acc[nt], 0, 0, 0);
            }
        }
        __syncthreads();
    }

    // epilogue: bias, src/dst dots, transpose via LDS -> B-fragment layout
    float s1[4] = {0.f, 0.f, 0.f, 0.f}, s2[4] = {0.f, 0.f, 0.f, 0.f};
    #pragma unroll
    for (int nt = 0; nt < 8; nt++) {
        #pragma unroll
        for (int r = 0; r < 4; r++) {
            float v = acc[nt][r] + bwv[nt];
            s1[r] += v * a1v[nt];
            s2[r] += v * a2v[nt];
            tb[nt * 16 + lm][w * 16 + q * 4 + r] = f2bf(v);   // tb[h][jrel]
        }
    }
    #pragma unroll
    for (int r = 0; r < 4; r++) {
        #pragma unroll
        for (int o = 1; o < 16; o <<= 1) {
            s1[r] += __shfl_xor(s1[r], o);
            s2[r] += __shfl_xor(s2[r], o);
        }
    }
    if (lm == 0) {
        #pragma unroll
        for (int r = 0; r < 4; r++) {
            long row = row0 + w * 16 + q * 4 + r;
            src[row] = (s1[r] + ba0) * LOG2E;   // fold bias-a + log2e (exp -> exp2)
            dst[row] = s2[r] * LOG2E;
        }
    }
    __syncthreads();
    // whF[b][jc][ht][l][e], frag = 512 shorts; block covers jc0..jc0+1
    const int b = (int)(row0 >> 11);
    const int jc0 = (int)((row0 & 2047) >> 5);
    const int f = tid >> 4;          // 0..15: jcrel = f>>3, ht = f&7
    const int sub = tid & 15;
    const int jcrel = f >> 3, ht = f & 7;
    const size_t fbase = (((size_t)b * 64 + jc0 + jcrel) * 8 + ht) * 512;
    #pragma unroll
    for (int i = 0; i < 4; i++) {
        int l = sub * 4 + i;
        uint4 v = *reinterpret_cast<const uint4*>(&tb[ht * 16 + (l & 15)][jcrel * 32 + (l >> 4) * 8]);
        *reinterpret_cast<uint4*>(whF + fbase + l * 8) = v;
    }
}

// ---------------- Kernel 2: merged pack + PAIR-scheduled MFMA attention ---
// 512 blocks (XCD-swizzled) x 256 threads (4 waves). Wave w owns i-rows
// i0+w*16..+15 AND packs those rows' adj, one 8-chunk group ahead.

// Raw barrier: LDS writes visible, VMEM prefetches NOT drained.
#define BAR()                                                                  \
    do {                                                                       \
        asm volatile("s_waitcnt lgkmcnt(0)" ::: "memory");                     \
        __builtin_amdgcn_s_barrier();                                          \
    } while (0)

#define ADJ_ISSUE(GNEXT, H)                                                    \
    do {                                                                       \
        _Pragma("unroll")                                                      \
        for (int r = 0; r < 8; r++) {                                          \
            const int* ap = adj +                                              \
                (size_t)(rowbase + wave * 16 + (H) * 8 + r) * NDIM +           \
                (GNEXT) * 256 + lane * 4;                                      \
            av[r] = ldnt(ap);                                                  \
        }                                                                      \
    } while (0)

#define ADJ_BALLOT(GNEXT, H)                                                   \
    do {                                                                       \
        _Pragma("unroll")                                                      \
        for (int r = 0; r < 8; r++) {                                          \
            unsigned long long b0 = __ballot(av[r][0] != 0);                   \
            unsigned long long b1 = __ballot(av[r][1] != 0);                   \
            unsigned long long b2 = __ballot(av[r][2] != 0);                   \
            unsigned long long b3 = __ballot(av[r][3] != 0);                   \
            if (lane < 8) {                                                    \
                unsigned long long bb = (lane < 2) ? b0                        \
                                        : (lane < 4) ? b1                      \
                                        : (lane < 6) ? b2 : b3;                \
                unsigned wv = (lane & 1) ? (unsigned)(bb >> 32) : (unsigned)bb;\
                maskB[(GNEXT) & 1][lane][wave * 16 + (H) * 8 + r] = wv;        \
            }                                                                  \
        }                                                                      \
    } while (0)

// Compute one 32-j chunk: T = global chunk, BUF = whS buffer (literal),
// C = chunk index within group (literal 0..7). md/d read direct from LDS.
#define COMP(T, BUF, C)                                                        \
    do {                                                                       \
        const int hi = ((C) & 4) ? 1 : 0;                                      \
        const int GB = (g8 >> 3) & 1;                                          \
        unsigned m0 = maskB[GB][0 + hi][wrow];                                 \
        unsigned m1 = maskB[GB][2 + hi][wrow];                                 \
        unsigned m2 = maskB[GB][4 + hi][wrow];                                 \
        unsigned m3 = maskB[GB][6 + hi][wrow];                                 \
        floatx4 dd0 = *reinterpret_cast<const floatx4*>(&dstS[(T) * 32 + q8]); \
        floatx4 dd1 =                                                          \
            *reinterpret_cast<const floatx4*>(&dstS[(T) * 32 + q8 + 4]);       \
        const int base = 8 * ((C) & 3) + 2 * q;                                \
        short8 af;                                                             \
        _Pragma("unroll")                                                      \
        for (int j = 0; j < 8; j++) {                                          \
            float x = si + ((j >> 2) ? dd1[j & 3] : dd0[j & 3]);               \
            x = fmaxf(x, 0.01f * x);            /* leaky, scale-invariant */   \
            float e2 = __builtin_amdgcn_exp2f(x);                              \
            unsigned mw = (j & 3) == 0 ? m0 : (j & 3) == 1 ? m1                \
                           : (j & 3) == 2 ? m2 : m3;                           \
            unsigned bit = (mw >> (base + (j >> 2))) & 1u;                     \
            float wgt = bit ? e2 : 0.f;                                        \
            lpart += wgt;                                                      \
            __hip_bfloat16 hb = __float2bfloat16(wgt); /* HW cvt, RNE */       \
            af[j] = *reinterpret_cast<short*>(&hb);                            \
        }                                                                      \
        _Pragma("unroll")                                                      \
        for (int hj = 0; hj < 8; hj++) {                                       \
            short8 fb = *reinterpret_cast<const short8*>(                      \
                &whS[BUF][hj * 512 + lane * 8]);                               \
            acc[hj] = __builtin_amdgcn_mfma_f32_16x16x32_bf16(af, fb,          \
                                                              acc[hj], 0, 0, 0); \
        }                                                                      \
    } while (0)

// Pair PI (literal 0..3): chunks T=g8+2*PI, T+1. One barrier per pair.
// Order: whF issue (T+2,T+3) -> adj duties (adj NEWER than whF -> pair's
// write-late keeps adj in flight) -> compute both chunks -> write -> BAR.
#define PAIR(PI)                                                               \
    do {                                                                       \
        const int T = g8 + (PI) * 2;                                           \
        constexpr int BUF0 = ((PI) & 1) * 2;                                   \
        constexpr int WBUF = ((((PI) & 1)) ^ 1) * 2;                           \
        short8 s0, s1, s2, s3;                                                 \
        if (T + 2 < 64) { /* issue whF stage loads for chunks T+2, T+3 */      \
            const unsigned short* gp = gsrc + (size_t)(T + 2) * 4096;          \
            s0 = *reinterpret_cast<const short8*>(gp);                         \
            s1 = *reinterpret_cast<const short8*>(gp + 512);                   \
            s2 = *reinterpret_cast<const short8*>(gp + 4096);                  \
            s3 = *reinterpret_cast<const short8*>(gp + 4096 + 512);            \
        }                                                                      \
        if ((PI) == 0 && g8 < 56) ADJ_ISSUE((g8 >> 3) + 1, 0);                 \
        if ((PI) == 1 && g8 < 56) {                                            \
            ADJ_BALLOT((g8 >> 3) + 1, 0);                                      \
            ADJ_ISSUE((g8 >> 3) + 1, 1);                                       \
        }                                                                      \
        if ((PI) == 3 && g8 < 56) ADJ_BALLOT((g8 >> 3) + 1, 1);                \
        COMP(T, BUF0, (PI) * 2);                                               \
        COMP(T + 1, BUF0 + 1, (PI) * 2 + 1);                                   \
        if (T + 2 < 64) { /* write-late: chunks T+2,T+3 -> other buf pair */   \
            *reinterpret_cast<short8*>(&whS[WBUF][pofs]) = s0;                 \
            *reinterpret_cast<short8*>(&whS[WBUF][pofs + 512]) = s1;           \
            *reinterpret_cast<short8*>(&whS[WBUF + 1][pofs]) = s2;             \
            *reinterpret_cast<short8*>(&whS[WBUF + 1][pofs + 512]) = s3;       \
        }                                                                      \
        BAR();                                                                 \
    } while (0)

__global__ __launch_bounds__(256) void k_attn(const int* __restrict__ adj,
                                              const unsigned short* __restrict__ whF,
                                              const float* __restrict__ src,
                                              const float* __restrict__ dst,
                                              float* __restrict__ out) {
    __shared__ short whS[4][4096];       // 32 KB: staged whF chunks, 4-deep
    __shared__ unsigned maskB[2][8][65]; // 4.1 KB: raw-ballot mask dbuf
    __shared__ float dstS[2048];         // 8 KB: dst batch-slice (prologue)
    __shared__ float lred[64];
    __shared__ float linv_s[64];

    const int tid = threadIdx.x;
    // XCD swizzle: 512 blocks, 8 XCDs -> XCD k gets a contiguous 64-block
    // chunk = batches 2k,2k+1. whF working set/XCD: 1 MB (L2-resident).
    const int bid = ((int)blockIdx.x & 7) * 64 + ((int)blockIdx.x >> 3);
    const int b = bid >> 5;                   // 32 i-tiles per batch
    const int i0 = (bid & 31) * 64;
    const int wave = tid >> 6, lane = tid & 63;
    const int lm = lane & 15, q = lane >> 4;
    const int q8 = q * 8;
    const int wrow = wave * 16 + lm;          // local i-row this lane owns
    const int rowbase = b * NDIM + i0;

    const float si = src[rowbase + wrow];     // includes ba and log2e scale
    // staging: chunk = 4096 shorts; wave w copies shorts [w*1024, +1024)
    const unsigned short* gsrc =
        whF + (size_t)b * 262144 + wave * 1024 + lane * 8;
    const int pofs = wave * 1024 + lane * 8;

    floatx4 acc[8];
    #pragma unroll
    for (int hj = 0; hj < 8; hj++) acc[hj] = (floatx4){0.f, 0.f, 0.f, 0.f};
    float lpart = 0.f;

    intx4 av[8];            // adj in-flight rows (8 rows x 256 cols)

    // prologue: dstS (all waves); whS chunks 0,1; pack group 0.
    {
        const float* dg = dst + b * NDIM;
        *reinterpret_cast<float4*>(&dstS[tid * 8]) =
            *reinterpret_cast<const float4*>(dg + tid * 8);
        *reinterpret_cast<float4*>(&dstS[tid * 8 + 4]) =
            *reinterpret_cast<const float4*>(dg + tid * 8 + 4);
    }
    {
        short8 p0 = *reinterpret_cast<const short8*>(gsrc);
        short8 p1 = *reinterpret_cast<const short8*>(gsrc + 512);
        short8 p2 = *reinterpret_cast<const short8*>(gsrc + 4096);
        short8 p3 = *reinterpret_cast<const short8*>(gsrc + 4096 + 512);
        *reinterpret_cast<short8*>(&whS[0][pofs]) = p0;
        *reinterpret_cast<short8*>(&whS[0][pofs + 512]) = p1;
        *reinterpret_cast<short8*>(&whS[1][pofs]) = p2;
        *reinterpret_cast<short8*>(&whS[1][pofs + 512]) = p3;
    }
    ADJ_ISSUE(0, 0);
    ADJ_BALLOT(0, 0);
    ADJ_ISSUE(0, 1);
    ADJ_BALLOT(0, 1);
    __syncthreads();

    for (int g8 = 0; g8 < 64; g8 += 8) {
        PAIR(0); PAIR(1); PAIR(2); PAIR(3);
    }

    // denominator: combine the 4 q-slices of each row
    lpart += __shfl_xor(lpart, 16);
    lpart += __shfl_xor(lpart, 32);
    if (q == 0) lred[wrow] = lpart;
    __syncthreads();
    if (tid < 64) {
        float l = lred[tid];
        linv_s[tid] = l > 0.f ? 1.f / l : 0.f;
    }
    __syncthreads();

    // epilogue: scale 1/l, ELU, store (C/D: col=lm -> h, row=q*4+r -> i)
    #pragma unroll
    for (int r = 0; r < 4; r++) {
        int il = wave * 16 + q * 4 + r;
        float li = linv_s[il];
        size_t obase = ((size_t)(rowbase + il)) * HDIM + lm;
        #pragma unroll
        for (int hj = 0; hj < 8; hj++) {
            float x = acc[hj][r] * li;
            x = x > 0.f ? x : (__expf(x) - 1.f);
            out[obase + hj * 16] = x;
        }
    }
}

extern "C" void kernel_launch(void* const* d_in, const int* in_sizes, int n_in,
                              void* d_out, int out_size, void* d_ws, size_t ws_size,
                              hipStream_t stream) {
    const float* X  = (const float*)d_in[0];   // [16,2048,256]
    const int* adj  = (const int*)d_in[1];     // [16,2048,2048]
    const float* W  = (const float*)d_in[2];   // [128,256]
    const float* bW = (const float*)d_in[3];   // [128]
    const float* a  = (const float*)d_in[4];   // [1,256]
    const float* ba = (const float*)d_in[5];   // [1]
    float* out = (float*)d_out;                // [16,2048,128]

    float* srcv = (float*)d_ws;                                    // B*N
    float* dstv = srcv + BDIM * NDIM;                              // B*N
    unsigned short* whF = (unsigned short*)(dstv + BDIM * NDIM);   // 8.4 MB bf16 frag-order

    k_wh<<<BDIM * NDIM / 64, 256, 0, stream>>>(X, W, bW, a, ba, srcv, dstv, whF);
    k_attn<<<BDIM * (NDIM / 64), 256, 0, stream>>>(adj, whF, srcv, dstv, out);
}

// Round 13
// 396.538 us; speedup vs baseline: 1.1535x; 1.0029x over previous
//
#include <hip/hip_runtime.h>
#include <hip/hip_bf16.h>

// GraphAttentionLayer: B=16, N=2048, F_IN=256, H=128 (fp32 in/out, adj int32)
//  k_wh  : MFMA bf16x3-split GEMM wh = X@W^T + bW; fused src/dst dots
//          (log2e + ba folded); writes wh in MFMA B-FRAGMENT order.
//  k_attn: R12 pair schedule -> QUAD (R13): 4 chunks per barrier, whS
//          8-deep (64KB LDS; total 76.6KB, still 2 blocks/CU of 160KB).
//          R12's residual leak: per-pair write-late queue [av8, whF4] had
//          adj OLDER than whF -> vmcnt drain at age ~1 pair. QUAD makes
//          every write-late queue [whF8, av8(newer)] -> vmcnt(8), adj never
//          force-drained; ballots wait at age = 1 quad (~1600cy > HBM).
//          Barriers 32->16. + T5 s_setprio(1) around each MFMA cluster
//          (phase-split schedule = enabling condition, m218b).
//          Raw {lgkmcnt;s_barrier}. Mask = raw-ballot maskB[bank][word][row]
//          (wave-private rows): bit_j of chunk C =
//          ballot_{j&3} >> (8(C&3)+2q+(j>>2)).

#define BDIM 16
#define NDIM 2048
#define FIN 256
#define HDIM 128
#define LOG2E 1.4426950408889634f

typedef short short8 __attribute__((ext_vector_type(8)));
typedef float floatx4 __attribute__((ext_vector_type(4)));
typedef int intx4 __attribute__((ext_vector_type(4)));

__device__ __forceinline__ unsigned short f2bf(float x) {
    unsigned int u = __float_as_uint(x);
    unsigned int r = (u + 0x7fffu + ((u >> 16) & 1u)) >> 16;  // RNE
    return (unsigned short)r;
}
__device__ __forceinline__ float bf2f(unsigned short s) {
    return __uint_as_float(((unsigned int)s) << 16);
}
__device__ __forceinline__ intx4 ldnt(const int* p) {
    return __builtin_nontemporal_load(reinterpret_cast<const intx4*>(p));
}

// ---------------- Kernel 1: wh via MFMA (bf16 hi/lo split) ----------------
// 64 rows x 128 h per block; 4 waves = 4 m-tiles of 16; K in panels of 64.
__global__ __launch_bounds__(256) void k_wh(const float* __restrict__ X,
                                            const float* __restrict__ W,
                                            const float* __restrict__ bW,
                                            const float* __restrict__ a,
                                            const float* __restrict__ ba_p,
                                            float* __restrict__ src,
                                            float* __restrict__ dst,
                                            unsigned short* __restrict__ whF) {
    __shared__ short lds[27648];                    // 54 KB
    short (*ah)[72] = (short(*)[72])lds;
    short (*al)[72] = (short(*)[72])(lds + 4608);
    short (*bh)[72] = (short(*)[72])(lds + 9216);
    short (*bl)[72] = (short(*)[72])(lds + 18432);
    short (*tb)[72] = (short(*)[72])lds;            // epilogue alias [128][72]

    const int tid = threadIdx.x;
    const long row0 = (long)blockIdx.x * 64;
    const int w = tid >> 6, lane = tid & 63;
    const int lm = lane & 15, q = lane >> 4;
    const float ba0 = ba_p[0];

    float a1v[8], a2v[8], bwv[8];
    #pragma unroll
    for (int nt = 0; nt < 8; nt++) {
        a1v[nt] = a[nt * 16 + lm];
        a2v[nt] = a[HDIM + nt * 16 + lm];
        bwv[nt] = bW[nt * 16 + lm];
    }

    floatx4 acc[8];
    #pragma unroll
    for (int nt = 0; nt < 8; nt++) acc[nt] = (floatx4){0.f, 0.f, 0.f, 0.f};

    for (int k0 = 0; k0 < FIN; k0 += 64) {
        #pragma unroll
        for (int u = 0; u < 4; u++) {
            int idx = tid + u * 256;
            int r = idx >> 4, fc = (idx & 15) * 4;
            float4 v = *reinterpret_cast<const float4*>(X + (row0 + r) * FIN + k0 + fc);
            union { unsigned short s[4]; uint2 u2; } ph, pl;
            ph.s[0] = f2bf(v.x); pl.s[0] = f2bf(v.x - bf2f(ph.s[0]));
            ph.s[1] = f2bf(v.y); pl.s[1] = f2bf(v.y - bf2f(ph.s[1]));
            ph.s[2] = f2bf(v.z); pl.s[2] = f2bf(v.z - bf2f(ph.s[2]));
            ph.s[3] = f2bf(v.w); pl.s[3] = f2bf(v.w - bf2f(ph.s[3]));
            *reinterpret_cast<uint2*>(&ah[r][fc]) = ph.u2;
            *reinterpret_cast<uint2*>(&al[r][fc]) = pl.u2;
        }
        #pragma unroll
        for (int u = 0; u < 8; u++) {
            int idx = tid + u * 256;
            int hh = idx >> 4, fc = (idx & 15) * 4;
            float4 v = *reinterpret_cast<const float4*>(W + hh * FIN + k0 + fc);
            union { unsigned short s[4]; uint2 u2; } ph, pl;
            ph.s[0] = f2bf(v.x); pl.s[0] = f2bf(v.x - bf2f(ph.s[0]));
            ph.s[1] = f2bf(v.y); pl.s[1] = f2bf(v.y - bf2f(ph.s[1]));
            ph.s[2] = f2bf(v.z); pl.s[2] = f2bf(v.z - bf2f(ph.s[2]));
            ph.s[3] = f2bf(v.w); pl.s[3] = f2bf(v.w - bf2f(ph.s[3]));
            *reinterpret_cast<uint2*>(&bh[hh][fc]) = ph.u2;
            *reinterpret_cast<uint2*>(&bl[hh][fc]) = pl.u2;
        }
        __syncthreads();
        #pragma unroll
        for (int ks = 0; ks < 64; ks += 32) {
            short8 afh = *reinterpret_cast<const short8*>(&ah[w * 16 + lm][ks + q * 8]);
            short8 afl = *reinterpret_cast<const short8*>(&al[w * 16 + lm][ks + q * 8]);
            #pragma unroll
            for (int nt = 0; nt < 8; nt++) {
                short8 bfh = *reinterpret_cast<const short8*>(&bh[nt * 16 + lm][ks + q * 8]);
                short8 bfl = *reinterpret_cast<const short8*>(&bl[nt * 16 + lm][ks + q * 8]);
                acc[nt] = __builtin_amdgcn_mfma_f32_16x16x32_bf16(afh, bfh, acc[nt], 0, 0, 0);
                acc[nt] = __builtin_amdgcn_mfma_f32_16x16x32_bf16(afh, bfl, acc[nt], 0, 0, 0);
                acc[nt] = __builtin_amdgcn_mfma_f32_16x16x32_bf16(afl, bfh, acc[nt], 0, 0, 0);
            }
        }
        __syncthreads();
    }

    // epilogue: bias, src/dst dots, transpose via LDS -> B-fragment layout
    float s1[4] = {0.f, 0.f, 0.f, 0.f}, s2[4] = {0.f, 0.f, 0.f, 0.f};
    #pragma unroll
    for (int nt = 0; nt < 8; nt++) {
        #pragma unroll
        for (int r = 0; r < 4; r++) {
            float v = acc[nt][r] + bwv[nt];
            s1[r] += v * a1v[nt];
            s2[r] += v * a2v[nt];
            tb[nt * 16 + lm][w * 16 + q * 4 + r] = f2bf(v);   // tb[h][jrel]
        }
    }
    #pragma unroll
    for (int r = 0; r < 4; r++) {
        #pragma unroll
        for (int o = 1; o < 16; o <<= 1) {
            s1[r] += __shfl_xor(s1[r], o);
            s2[r] += __shfl_xor(s2[r], o);
        }
    }
    if (lm == 0) {
        #pragma unroll
        for (int r = 0; r < 4; r++) {
            long row = row0 + w * 16 + q * 4 + r;
            src[row] = (s1[r] + ba0) * LOG2E;   // fold bias-a + log2e (exp -> exp2)
            dst[row] = s2[r] * LOG2E;
        }
    }
    __syncthreads();
    // whF[b][jc][ht][l][e], frag = 512 shorts; block covers jc0..jc0+1
    const int b = (int)(row0 >> 11);
    const int jc0 = (int)((row0 & 2047) >> 5);
    const int f = tid >> 4;          // 0..15: jcrel = f>>3, ht = f&7
    const int sub = tid & 15;
    const int jcrel = f >> 3, ht = f & 7;
    const size_t fbase = (((size_t)b * 64 + jc0 + jcrel) * 8 + ht) * 512;
    #pragma unroll
    for (int i = 0; i < 4; i++) {
        int l = sub * 4 + i;
        uint4 v = *reinterpret_cast<const uint4*>(&tb[ht * 16 + (l & 15)][jcrel * 32 + (l >> 4) * 8]);
        *reinterpret_cast<uint4*>(whF + fbase + l * 8) = v;
    }
}

// ---------------- Kernel 2: merged pack + QUAD-scheduled MFMA attention ---
// 512 blocks (XCD-swizzled) x 256 threads (4 waves). Wave w owns i-rows
// i0+w*16..+15 AND packs those rows' adj, one 8-chunk group ahead.

// Raw barrier: LDS writes visible, VMEM prefetches NOT drained.
#define BAR()                                                                  \
    do {                                                                       \
        asm volatile("s_waitcnt lgkmcnt(0)" ::: "memory");                     \
        __builtin_amdgcn_s_barrier();                                          \
    } while (0)

#define ADJ_ISSUE(GNEXT, H)                                                    \
    do {                                                                       \
        _Pragma("unroll")                                                      \
        for (int r = 0; r < 8; r++) {                                          \
            const int* ap = adj +                                              \
                (size_t)(rowbase + wave * 16 + (H) * 8 + r) * NDIM +           \
                (GNEXT) * 256 + lane * 4;                                      \
            av[r] = ldnt(ap);                                                  \
        }                                                                      \
    } while (0)

#define ADJ_BALLOT(GNEXT, H)                                                   \
    do {                                                                       \
        _Pragma("unroll")                                                      \
        for (int r = 0; r < 8; r++) {                                          \
            unsigned long long b0 = __ballot(av[r][0] != 0);                   \
            unsigned long long b1 = __ballot(av[r][1] != 0);                   \
            unsigned long long b2 = __ballot(av[r][2] != 0);                   \
            unsigned long long b3 = __ballot(av[r][3] != 0);                   \
            if (lane < 8) {                                                    \
                unsigned long long bb = (lane < 2) ? b0                        \
                                        : (lane < 4) ? b1                      \
                                        : (lane < 6) ? b2 : b3;                \
                unsigned wv = (lane & 1) ? (unsigned)(bb >> 32) : (unsigned)bb;\
                maskB[(GNEXT) & 1][lane][wave * 16 + (H) * 8 + r] = wv;        \
            }                                                                  \
        }                                                                      \
    } while (0)

// Compute one 32-j chunk: T = global chunk, BUF = whS buffer (literal),
// C = chunk index within group (literal 0..7). md/d read direct from LDS.
#define COMP(T, BUF, C)                                                        \
    do {                                                                       \
        const int hi = ((C) & 4) ? 1 : 0;                                      \
        const int GB = (g8 >> 3) & 1;                                          \
        unsigned m0 = maskB[GB][0 + hi][wrow];                                 \
        unsigned m1 = maskB[GB][2 + hi][wrow];                                 \
        unsigned m2 = maskB[GB][4 + hi][wrow];                                 \
        unsigned m3 = maskB[GB][6 + hi][wrow];                                 \
        floatx4 dd0 = *reinterpret_cast<const floatx4*>(&dstS[(T) * 32 + q8]); \
        floatx4 dd1 =                                                          \
            *reinterpret_cast<const floatx4*>(&dstS[(T) * 32 + q8 + 4]);       \
        const int base = 8 * ((C) & 3) + 2 * q;                                \
        short8 af;                                                             \
        _Pragma("unroll")                                                      \
        for (int j = 0; j < 8; j++) {                                          \
            float x = si + ((j >> 2) ? dd1[j & 3] : dd0[j & 3]);               \
            x = fmaxf(x, 0.01f * x);            /* leaky, scale-invariant */   \
            float e2 = __builtin_amdgcn_exp2f(x);                              \
            unsigned mw = (j & 3) == 0 ? m0 : (j & 3) == 1 ? m1                \
                           : (j & 3) == 2 ? m2 : m3;                           \
            unsigned bit = (mw >> (base + (j >> 2))) & 1u;                     \
            float wgt = bit ? e2 : 0.f;                                        \
            lpart += wgt;                                                      \
            __hip_bfloat16 hb = __float2bfloat16(wgt); /* HW cvt, RNE */       \
            af[j] = *reinterpret_cast<short*>(&hb);                            \
        }                                                                      \
        __builtin_amdgcn_s_setprio(1);  /* T5: favor MFMA cluster */           \
        _Pragma("unroll")                                                      \
        for (int hj = 0; hj < 8; hj++) {                                       \
            short8 fb = *reinterpret_cast<const short8*>(                      \
                &whS[BUF][hj * 512 + lane * 8]);                               \
            acc[hj] = __builtin_amdgcn_mfma_f32_16x16x32_bf16(af, fb,          \
                                                              acc[hj], 0, 0, 0); \
        }                                                                      \
        __builtin_amdgcn_s_setprio(0);                                         \
    } while (0)

// Quad QI (literal 0/1): chunks T0=g8+4*QI .. T0+3. One barrier per quad.
// Queue at write-late is ALWAYS [whF8, av8(newer)] -> vmcnt(8) keeps adj
// in flight; ballots wait at age = 1 quad (~1600cy). Mask is wave-private
// so ballot(G,H1) pre-COMP at Q0 needs only program-order lgkmcnt.
#define QUAD(QI)                                                               \
    do {                                                                       \
        const int T0 = g8 + (QI) * 4;                                          \
        constexpr int RBUF = (QI) * 4;                                         \
        constexpr int WBUF = 4 - (QI) * 4;                                     \
        short8 s0, s1, s2, s3, s4, s5, s6, s7;                                 \
        if (T0 + 4 < 64) { /* issue whF loads for chunks T0+4..T0+7 */         \
            const unsigned short* gp = gsrc + (size_t)(T0 + 4) * 4096;         \
            s0 = *reinterpret_cast<const short8*>(gp);                         \
            s1 = *reinterpret_cast<const short8*>(gp + 512);                   \
            s2 = *reinterpret_cast<const short8*>(gp + 4096);                  \
            s3 = *reinterpret_cast<const short8*>(gp + 4096 + 512);            \
            s4 = *reinterpret_cast<const short8*>(gp + 8192);                  \
            s5 = *reinterpret_cast<const short8*>(gp + 8192 + 512);            \
            s6 = *reinterpret_cast<const short8*>(gp + 12288);                 \
            s7 = *reinterpret_cast<const short8*>(gp + 12288 + 512);           \
        }                                                                      \
        if ((QI) == 0) {                                                       \
            if (g8 > 0) ADJ_BALLOT(g8 >> 3, 1);  /* H1 of CURRENT group */     \
            if (g8 < 56) ADJ_ISSUE((g8 >> 3) + 1, 0);                          \
        } else {                                                               \
            if (g8 < 56) {                                                     \
                ADJ_BALLOT((g8 >> 3) + 1, 0);                                  \
                ADJ_ISSUE((g8 >> 3) + 1, 1);                                   \
            }                                                                  \
        }                                                                      \
        COMP(T0, RBUF + 0, (QI) * 4 + 0);                                      \
        COMP(T0 + 1, RBUF + 1, (QI) * 4 + 1);                                  \
        COMP(T0 + 2, RBUF + 2, (QI) * 4 + 2);                                  \
        COMP(T0 + 3, RBUF + 3, (QI) * 4 + 3);                                  \
        if (T0 + 4 < 64) { /* write-late: chunks T0+4..T0+7 -> other 4 bufs */ \
            *reinterpret_cast<short8*>(&whS[WBUF][pofs]) = s0;                 \
            *reinterpret_cast<short8*>(&whS[WBUF][pofs + 512]) = s1;           \
            *reinterpret_cast<short8*>(&whS[WBUF + 1][pofs]) = s2;             \
            *reinterpret_cast<short8*>(&whS[WBUF + 1][pofs + 512]) = s3;       \
            *reinterpret_cast<short8*>(&whS[WBUF + 2][pofs]) = s4;             \
            *reinterpret_cast<short8*>(&whS[WBUF + 2][pofs + 512]) = s5;       \
            *reinterpret_cast<short8*>(&whS[WBUF + 3][pofs]) = s6;             \
            *reinterpret_cast<short8*>(&whS[WBUF + 3][pofs + 512]) = s7;       \
        }                                                                      \
        BAR();                                                                 \
    } while (0)

__global__ __launch_bounds__(256) void k_attn(const int* __restrict__ adj,
                                              const unsigned short* __restrict__ whF,
                                              const float* __restrict__ src,
                                              const float* __restrict__ dst,
                                              float* __restrict__ out) {
    __shared__ short whS[8][4096];       // 64 KB: staged whF chunks, 8-deep
    __shared__ unsigned maskB[2][8][65]; // 4.1 KB: raw-ballot mask dbuf
    __shared__ float dstS[2048];         // 8 KB: dst batch-slice (prologue)
    __shared__ float lred[64];
    __shared__ float linv_s[64];

    const int tid = threadIdx.x;
    // XCD swizzle: 512 blocks, 8 XCDs -> XCD k gets a contiguous 64-block
    // chunk = batches 2k,2k+1. whF working set/XCD: 1 MB (L2-resident).
    const int bid = ((int)blockIdx.x & 7) * 64 + ((int)blockIdx.x >> 3);
    const int b = bid >> 5;                   // 32 i-tiles per batch
    const int i0 = (bid & 31) * 64;
    const int wave = tid >> 6, lane = tid & 63;
    const int lm = lane & 15, q = lane >> 4;
    const int q8 = q * 8;
    const int wrow = wave * 16 + lm;          // local i-row this lane owns
    const int rowbase = b * NDIM + i0;

    const float si = src[rowbase + wrow];     // includes ba and log2e scale
    // staging: chunk = 4096 shorts; wave w copies shorts [w*1024, +1024)
    const unsigned short* gsrc =
        whF + (size_t)b * 262144 + wave * 1024 + lane * 8;
    const int pofs = wave * 1024 + lane * 8;

    floatx4 acc[8];
    #pragma unroll
    for (int hj = 0; hj < 8; hj++) acc[hj] = (floatx4){0.f, 0.f, 0.f, 0.f};
    float lpart = 0.f;

    intx4 av[8];            // adj in-flight rows (8 rows x 256 cols)

    // prologue: dstS (all waves); whS chunks 0-3; pack group 0.
    {
        const float* dg = dst + b * NDIM;
        *reinterpret_cast<float4*>(&dstS[tid * 8]) =
            *reinterpret_cast<const float4*>(dg + tid * 8);
        *reinterpret_cast<float4*>(&dstS[tid * 8 + 4]) =
            *reinterpret_cast<const float4*>(dg + tid * 8 + 4);
    }
    {
        short8 p0 = *reinterpret_cast<const short8*>(gsrc);
        short8 p1 = *reinterpret_cast<const short8*>(gsrc + 512);
        short8 p2 = *reinterpret_cast<const short8*>(gsrc + 4096);
        short8 p3 = *reinterpret_cast<const short8*>(gsrc + 4096 + 512);
        short8 p4 = *reinterpret_cast<const short8*>(gsrc + 8192);
        short8 p5 = *reinterpret_cast<const short8*>(gsrc + 8192 + 512);
        short8 p6 = *reinterpret_cast<const short8*>(gsrc + 12288);
        short8 p7 = *reinterpret_cast<const short8*>(gsrc + 12288 + 512);
        *reinterpret_cast<short8*>(&whS[0][pofs]) = p0;
        *reinterpret_cast<short8*>(&whS[0][pofs + 512]) = p1;
        *reinterpret_cast<short8*>(&whS[1][pofs]) = p2;
        *reinterpret_cast<short8*>(&whS[1][pofs + 512]) = p3;
        *reinterpret_cast<short8*>(&whS[2][pofs]) = p4;
        *reinterpret_cast<short8*>(&whS[2][pofs + 512]) = p5;
        *reinterpret_cast<short8*>(&whS[3][pofs]) = p6;
        *reinterpret_cast<short8*>(&whS[3][pofs + 512]) = p7;
    }
    ADJ_ISSUE(0, 0);
    ADJ_BALLOT(0, 0);
    ADJ_ISSUE(0, 1);
    ADJ_BALLOT(0, 1);
    __syncthreads();

    for (int g8 = 0; g8 < 64; g8 += 8) {
        QUAD(0);
        QUAD(1);
    }

    // denominator: combine the 4 q-slices of each row
    lpart += __shfl_xor(lpart, 16);
    lpart += __shfl_xor(lpart, 32);
    if (q == 0) lred[wrow] = lpart;
    __syncthreads();
    if (tid < 64) {
        float l = lred[tid];
        linv_s[tid] = l > 0.f ? 1.f / l : 0.f;
    }
    __syncthreads();

    // epilogue: scale 1/l, ELU, store (C/D: col=lm -> h, row=q*4+r -> i)
    #pragma unroll
    for (int r = 0; r < 4; r++) {
        int il = wave * 16 + q * 4 + r;
        float li = linv_s[il];
        size_t obase = ((size_t)(rowbase + il)) * HDIM + lm;
        #pragma unroll
        for (int hj = 0; hj < 8; hj++) {
            float x = acc[hj][r] * li;
            x = x > 0.f ? x : (__expf(x) - 1.f);
            out[obase + hj * 16] = x;
        }
    }
}

extern "C" void kernel_launch(void* const* d_in, const int* in_sizes, int n_in,
                              void* d_out, int out_size, void* d_ws, size_t ws_size,
                              hipStream_t stream) {
    const float* X  = (const float*)d_in[0];   // [16,2048,256]
    const int* adj  = (const int*)d_in[1];     // [16,2048,2048]
    const float* W  = (const float*)d_in[2];   // [128,256]
    const float* bW = (const float*)d_in[3];   // [128]
    const float* a  = (const float*)d_in[4];   // [1,256]
    const float* ba = (const float*)d_in[5];   // [1]
    float* out = (float*)d_out;                // [16,2048,128]

    float* srcv = (float*)d_ws;                                    // B*N
    float* dstv = srcv + BDIM * NDIM;                              // B*N
    unsigned short* whF = (unsigned short*)(dstv + BDIM * NDIM);   // 8.4 MB bf16 frag-order

    k_wh<<<BDIM * NDIM / 64, 256, 0, stream>>>(X, W, bW, a, ba, srcv, dstv, whF);
    k_attn<<<BDIM * (NDIM / 64), 256, 0, stream>>>(adj, whF, srcv, dstv, out);
}